// Round 1
// baseline (476.160 us; speedup 1.0000x reference)
//
#include <hip/hip_runtime.h>
#include <hip/hip_bf16.h>
#include <stdint.h>

#define BB 32768
#define NN 512
#define CG_ITERS_PER_PHASE 6   // 2 phases (K1, K2) -> 12 total; kappa~5 => err ~2e-5

typedef __attribute__((ext_vector_type(8))) short bf16x8;
typedef __attribute__((ext_vector_type(4))) float f32x4;

// async global->LDS, 16B per lane. LDS dest must be wave-uniform base + lane*16.
__device__ __forceinline__ void gld_lds16(const void* g, void* l) {
  typedef __attribute__((address_space(1))) const unsigned int gas_u32;
  typedef __attribute__((address_space(3))) unsigned int las_u32;
  __builtin_amdgcn_global_load_lds((gas_u32*)(uintptr_t)g,
                                   (las_u32*)(uint32_t)(uintptr_t)l, 16, 0, 0);
}

__device__ __forceinline__ float wave_reduce(float v) {
#pragma unroll
  for (int off = 32; off > 0; off >>= 1) v += __shfl_xor(v, off, 64);
  return v;
}

// CG on Gamma v = SR, 512 threads (8 waves), vectors in LDS, Gamma fp32 from global.
// sm needs (4*512 + 16) floats.
__device__ void cg_phase(const float* __restrict__ Gamma, const float* __restrict__ SR,
                         float* __restrict__ st_x, float* __restrict__ st_r,
                         float* __restrict__ st_p, float* __restrict__ st_rr,
                         float* __restrict__ v_out, float* sm, int first_phase) {
  float* sx = sm;
  float* sr = sm + 512;
  float* sp = sm + 1024;
  float* sAp = sm + 1536;
  float* red = sm + 2048;  // 16 floats
  const int t = threadIdx.x;
  const int wv = t >> 6, ln = t & 63;
  float rr;
  if (first_phase) {
    float s = SR[t];
    sx[t] = 0.f; sr[t] = s; sp[t] = s;
    float pv = wave_reduce(s * s);
    if (ln == 0) red[wv] = pv;
    __syncthreads();
    if (t == 0) { float a = 0; for (int i = 0; i < 8; ++i) a += red[i]; red[8] = a; }
    __syncthreads();
    rr = red[8];
  } else {
    sx[t] = st_x[t]; sr[t] = st_r[t]; sp[t] = st_p[t];
    rr = st_rr[0];
    __syncthreads();
  }
  for (int it = 0; it < CG_ITERS_PER_PHASE; ++it) {
    // Ap = Gamma * p ; wave wv handles rows wv*64..wv*64+63
    float4 pa = *(const float4*)&sp[4 * ln];
    float4 pb = *(const float4*)&sp[256 + 4 * ln];
#pragma unroll 2
    for (int rI = 0; rI < 64; ++rI) {
      int row = wv * 64 + rI;
      const float4* g4 = (const float4*)(Gamma + (size_t)row * NN);
      float4 ga = g4[ln];
      float4 gb = g4[64 + ln];
      float d = ga.x * pa.x + ga.y * pa.y + ga.z * pa.z + ga.w * pa.w +
                gb.x * pb.x + gb.y * pb.y + gb.z * pb.z + gb.w * pb.w;
      d = wave_reduce(d);
      if (ln == 0) sAp[row] = d;
    }
    __syncthreads();
    float pv = wave_reduce(sp[t] * sAp[t]);
    if (ln == 0) red[wv] = pv;
    __syncthreads();
    if (t == 0) { float a = 0; for (int i = 0; i < 8; ++i) a += red[i]; red[8] = a; }
    __syncthreads();
    float alpha = rr / red[8];
    float xn = sx[t] + alpha * sp[t];
    float rn = sr[t] - alpha * sAp[t];
    sx[t] = xn; sr[t] = rn;
    float rv = wave_reduce(rn * rn);
    if (ln == 0) red[wv] = rv;
    __syncthreads();
    if (t == 0) { float a = 0; for (int i = 0; i < 8; ++i) a += red[i]; red[9] = a; }
    __syncthreads();
    float rrn = red[9];
    float beta = rrn / rr;
    sp[t] = rn + beta * sp[t];
    rr = rrn;
    __syncthreads();
  }
  st_x[t] = sx[t]; st_r[t] = sr[t]; st_p[t] = sp[t];
  if (t == 0) st_rr[0] = rr;
  if (!first_phase) v_out[t] = sx[t];
}

// K1: r = exp(sigma - lsh) fp32 -> bf16, write transposed Rt[N][B]; column sums; CG phase 1.
__global__ __launch_bounds__(512) void k1_rexp(
    const float* __restrict__ lsh, const float* __restrict__ sig,
    const float* __restrict__ SR, const float* __restrict__ Gamma,
    __hip_bfloat16* __restrict__ Rt, float* __restrict__ colsum,
    float* st_x, float* st_r, float* st_p, float* st_rr) {
  __shared__ __align__(16) unsigned char smraw[25600];
  if (blockIdx.x == 0) {
    cg_phase(Gamma, SR, st_x, st_r, st_p, st_rr, nullptr, (float*)smraw, 1);
    return;
  }
  __hip_bfloat16* tile = (__hip_bfloat16*)smraw;  // [64 j][136 b] (pad 8 keeps 16B align)
  float* scr = (float*)(smraw + 64 * 136 * 2);    // [32][64]
  const int t = threadIdx.x;
  const int bb = (blockIdx.x - 1) * 128;
  const int tc = t & 15, tg = t >> 4;  // tc: col-quad, tg: 0..31 row group
  for (int jt = 0; jt < 8; ++jt) {
    const int j0 = jt * 64;
    float cs0 = 0, cs1 = 0, cs2 = 0, cs3 = 0;
#pragma unroll
    for (int itp = 0; itp < 4; ++itp) {
      const int bl = tg + 32 * itp;
      const size_t off = (size_t)(bb + bl) * NN + j0 + 4 * tc;
      float4 sv = *(const float4*)(sig + off);
      float4 lv = *(const float4*)(lsh + off);
      float r0 = __expf(sv.x - lv.x), r1 = __expf(sv.y - lv.y);
      float r2 = __expf(sv.z - lv.z), r3 = __expf(sv.w - lv.w);
      cs0 += r0; cs1 += r1; cs2 += r2; cs3 += r3;
      tile[(4 * tc + 0) * 136 + bl] = __float2bfloat16(r0);
      tile[(4 * tc + 1) * 136 + bl] = __float2bfloat16(r1);
      tile[(4 * tc + 2) * 136 + bl] = __float2bfloat16(r2);
      tile[(4 * tc + 3) * 136 + bl] = __float2bfloat16(r3);
    }
    scr[tg * 64 + 4 * tc + 0] = cs0;
    scr[tg * 64 + 4 * tc + 1] = cs1;
    scr[tg * 64 + 4 * tc + 2] = cs2;
    scr[tg * 64 + 4 * tc + 3] = cs3;
    __syncthreads();
#pragma unroll
    for (int ps = 0; ps < 2; ++ps) {
      const int jl = tg + 32 * ps;
      uint4 vv = *(const uint4*)(tile + jl * 136 + tc * 8);
      *(uint4*)(Rt + (size_t)(j0 + jl) * BB + bb + tc * 8) = vv;
    }
    if (t < 64) {
      float s = 0;
#pragma unroll
      for (int g = 0; g < 32; ++g) s += scr[g * 64 + t];
      atomicAdd(&colsum[j0 + t], s);
    }
    __syncthreads();
  }
}

// K2: C += Rt_panel_i * Rt_panel_j^T via bf16 MFMA; CG phase 2 in block 0.
__global__ __launch_bounds__(512) void k2_syrk(
    const __hip_bfloat16* __restrict__ Rt, const float* __restrict__ Gamma,
    float* __restrict__ Cws, float* st_x, float* st_r, float* st_p, float* st_rr,
    float* __restrict__ v_out) {
  __shared__ __align__(16) unsigned char smraw[32768];
  if (blockIdx.x == 0) {
    cg_phase(Gamma, nullptr, st_x, st_r, st_p, st_rr, v_out, (float*)smraw, 0);
    return;
  }
  if (threadIdx.x >= 256) return;  // gemm path uses 4 waves
  __hip_bfloat16* As = (__hip_bfloat16*)smraw;  // [128 i][64 k]
  __hip_bfloat16* Bs = As + 128 * 64;           // [128 j][64 k]
  const int t = threadIdx.x;
  const int blin = blockIdx.x - 1;
  const int tile = blin & 15, kc = blin >> 4;
  const int i0 = (tile & 3) * 128, j0 = (tile >> 2) * 128;
  const size_t b0 = (size_t)kc * 2048;
  const int lane = t & 63, wv = t >> 6;
  const int wi = (wv >> 1) * 64, wj = (wv & 1) * 64;
  const int lm = lane & 15, lq = lane >> 4;
  const int sri = t >> 3, sc = (t & 7) * 8;  // staging: row group, 16B chunk
  f32x4 acc[4][4];
#pragma unroll
  for (int a = 0; a < 4; ++a)
#pragma unroll
    for (int b = 0; b < 4; ++b) acc[a][b] = (f32x4){0.f, 0.f, 0.f, 0.f};

  for (int ks = 0; ks < 32; ++ks) {
    const size_t bcur = b0 + ks * 64;
#pragma unroll
    for (int shot = 0; shot < 4; ++shot) {
      const int il = sri + 32 * shot;
      gld_lds16(Rt + (size_t)(i0 + il) * BB + bcur + sc, As + il * 64 + sc);
      gld_lds16(Rt + (size_t)(j0 + il) * BB + bcur + sc, Bs + il * 64 + sc);
    }
    __syncthreads();
#pragma unroll
    for (int s = 0; s < 2; ++s) {
      bf16x8 af[4], bfr[4];
#pragma unroll
      for (int g = 0; g < 4; ++g) {
        af[g] = *(const bf16x8*)(As + (wi + g * 16 + lm) * 64 + s * 32 + lq * 8);
        bfr[g] = *(const bf16x8*)(Bs + (wj + g * 16 + lm) * 64 + s * 32 + lq * 8);
      }
#pragma unroll
      for (int gm = 0; gm < 4; ++gm)
#pragma unroll
        for (int gn = 0; gn < 4; ++gn)
          acc[gm][gn] = __builtin_amdgcn_mfma_f32_16x16x32_bf16(af[gm], bfr[gn], acc[gm][gn], 0, 0, 0);
    }
    __syncthreads();
  }
  // C/D layout: col = lane&15, row = (lane>>4)*4 + reg
#pragma unroll
  for (int gm = 0; gm < 4; ++gm) {
    const int rbase = i0 + wi + gm * 16 + lq * 4;
#pragma unroll
    for (int gn = 0; gn < 4; ++gn) {
      const int cidx = j0 + wj + gn * 16 + lm;
#pragma unroll
      for (int e = 0; e < 4; ++e)
        atomicAdd(&Cws[(size_t)(rbase + e) * NN + cidx], acc[gm][gn][e]);
    }
  }
}

// K3: secondsum = sum_ij v_i Gamma_ij v_j C_ij
__global__ __launch_bounds__(256) void k3_contract(
    const float* __restrict__ Gamma, const float* __restrict__ Cws,
    const float* __restrict__ v, float* __restrict__ secondsum) {
  __shared__ float red[4];
  const int t = threadIdx.x;
  const size_t e = ((size_t)blockIdx.x * 256 + t) * 4;
  const int i = (int)(e >> 9), j = (int)(e & 511);
  float4 g = *(const float4*)(Gamma + e);
  float4 c = *(const float4*)(Cws + e);
  float4 vj = *(const float4*)(v + j);
  float vi = v[i];
  float p = vi * (g.x * c.x * vj.x + g.y * c.y * vj.y + g.z * c.z * vj.z + g.w * c.w * vj.w);
  p = wave_reduce(p);
  if ((t & 63) == 0) red[t >> 6] = p;
  __syncthreads();
  if (t == 0) atomicAdd(secondsum, red[0] + red[1] + red[2] + red[3]);
}

// K4: loss = -( sum_j (colsum_j/B) v_j SR_j / k  -  secondsum/(B*2k) )
__global__ __launch_bounds__(512) void k4_final(
    const float* __restrict__ colsum, const float* __restrict__ v,
    const float* __restrict__ SR, const float* __restrict__ secondsum,
    const int* __restrict__ kp, float* __restrict__ out) {
  __shared__ float red[8];
  const int t = threadIdx.x;
  float f = (colsum[t] * (1.0f / BB)) * v[t] * SR[t];
  f = wave_reduce(f);
  if ((t & 63) == 0) red[t >> 6] = f;
  __syncthreads();
  if (t == 0) {
    float first = 0;
#pragma unroll
    for (int i = 0; i < 8; ++i) first += red[i];
    float kk = (float)kp[0];
    float sec = secondsum[0] / ((float)BB * 2.0f * kk);
    out[0] = -(first / kk - sec);
  }
}

extern "C" void kernel_launch(void* const* d_in, const int* in_sizes, int n_in,
                              void* d_out, int out_size, void* d_ws, size_t ws_size,
                              hipStream_t stream) {
  const float* lsh = (const float*)d_in[0];
  const float* sig = (const float*)d_in[1];
  const float* SR = (const float*)d_in[2];
  const float* Gam = (const float*)d_in[3];
  const int* kp = (const int*)d_in[4];
  char* ws = (char*)d_ws;
  float* Cws = (float*)ws;                          // 1 MB
  float* colsum = (float*)(ws + (1 << 20));         // 2 KB
  float* secsum = (float*)(ws + (1 << 20) + 2048);  // 4 B
  float* st_x = (float*)(ws + (1 << 20) + 4096);
  float* st_r = st_x + 512;
  float* st_p = st_r + 512;
  float* st_rr = st_p + 512;
  float* v = st_rr + 64;
  __hip_bfloat16* Rt = (__hip_bfloat16*)(ws + (2 << 20));  // 32 MB

  hipMemsetAsync(d_ws, 0, (1 << 20) + 4096, stream);  // zero C, colsum, secsum
  k1_rexp<<<257, 512, 0, stream>>>(lsh, sig, SR, Gam, Rt, colsum, st_x, st_r, st_p, st_rr);
  k2_syrk<<<257, 512, 0, stream>>>(Rt, Gam, Cws, st_x, st_r, st_p, st_rr, v);
  k3_contract<<<256, 256, 0, stream>>>(Gam, Cws, v, secsum);
  k4_final<<<1, 512, 0, stream>>>(colsum, v, SR, secsum, kp, (float*)d_out);
}

// Round 2
// 297.401 us; speedup vs baseline: 1.6011x; 1.6011x over previous
//
#include <hip/hip_runtime.h>
#include <hip/hip_bf16.h>
#include <stdint.h>

#define BB 32768
#define NN 512
#define CG1 7
#define CG2 3

typedef __attribute__((ext_vector_type(8))) short bf16x8;
typedef __attribute__((ext_vector_type(4))) float f32x4;

__device__ __forceinline__ void gld_lds16(const void* g, void* l) {
  typedef __attribute__((address_space(1))) const unsigned int gas_u32;
  typedef __attribute__((address_space(3))) unsigned int las_u32;
  __builtin_amdgcn_global_load_lds((gas_u32*)(uintptr_t)g,
                                   (las_u32*)(uint32_t)(uintptr_t)l, 16, 0, 0);
}

__device__ __forceinline__ unsigned short f2bf(float x) {
  __hip_bfloat16 h = __float2bfloat16(x);
  return *reinterpret_cast<unsigned short*>(&h);
}

__device__ __forceinline__ float wave_reduce(float v) {
#pragma unroll
  for (int off = 32; off > 0; off >>= 1) v += __shfl_xor(v, off, 64);
  return v;
}

__device__ __forceinline__ float block_reduce(float v, float* red) {
  v = wave_reduce(v);
  const int wv = threadIdx.x >> 6, ln = threadIdx.x & 63;
  if (ln == 0) red[wv] = v;
  __syncthreads();
  if (threadIdx.x == 0) {
    float a = 0;
#pragma unroll
    for (int i = 0; i < 8; ++i) a += red[i];
    red[8] = a;
  }
  __syncthreads();
  return red[8];
}

// CG on Gamma v = SR. 512 threads. Matvec uses symmetry: Ap[i] = sum_j G[j][i] p[j],
// column-major coalesced float4 loads, no shuffles in inner loop.
// sm needs 2576 floats: sp[512], apw[4*512], red[16].
__device__ void cg_phase(const float* __restrict__ Gamma, const float* __restrict__ SR,
                         float* __restrict__ st, float* __restrict__ v_out,
                         float* sm, int first, int iters) {
  float* sp = sm;
  float* apw = sm + 512;
  float* red = sm + 2560;
  const int t = threadIdx.x;
  const int rg = t >> 7;          // 0..3, wave-uniform
  const int c0 = (t & 127) * 4;   // 4 columns owned
  float x, r, p, rr;
  if (first) {
    float s = SR[t];
    x = 0.f; r = s; p = s;
    rr = block_reduce(s * s, red);
  } else {
    x = st[t]; r = st[512 + t]; p = st[1024 + t]; rr = st[1536];
  }
  for (int it = 0; it < iters; ++it) {
    sp[t] = p;
    __syncthreads();
    float a0 = 0, a1 = 0, a2 = 0, a3 = 0;
    for (int j = 0; j < NN; j += 32) {
#pragma unroll
      for (int jj = 0; jj < 8; ++jj) {
        const int row = j + jj * 4 + rg;
        float4 g = *(const float4*)(Gamma + row * NN + c0);
        float pv = sp[row];
        a0 += g.x * pv; a1 += g.y * pv; a2 += g.z * pv; a3 += g.w * pv;
      }
    }
    *(float4*)(apw + rg * 512 + c0) = make_float4(a0, a1, a2, a3);
    __syncthreads();
    float ap = apw[t] + apw[512 + t] + apw[1024 + t] + apw[1536 + t];
    float pAp = block_reduce(p * ap, red);
    float alpha = rr / pAp;
    x += alpha * p;
    r -= alpha * ap;
    float rrn = block_reduce(r * r, red);
    float beta = rrn / rr;
    p = r + beta * p;
    rr = rrn;
    __syncthreads();
  }
  if (v_out) {
    v_out[t] = x;
  } else {
    st[t] = x; st[512 + t] = r; st[1024 + t] = p;
    if (t == 0) st[1536] = rr;
  }
}

// K1: r = exp(sigma - lsh), write transposed Rt[N][B] bf16, colsum buckets; block 0: CG phase 1.
__global__ __launch_bounds__(512) void k1_rexp(
    const float* __restrict__ lsh, const float* __restrict__ sig,
    const float* __restrict__ SR, const float* __restrict__ Gamma,
    unsigned short* __restrict__ Rt, float* __restrict__ colsum,
    float* __restrict__ cgst) {
  __shared__ __align__(16) float sm[4352];
  if (blockIdx.x == 0) {
    cg_phase(Gamma, SR, cgst, nullptr, sm, 1, CG1);
    return;
  }
  unsigned short* tile = (unsigned short*)sm;  // [64 j][68 b] ushort
  float* scr = sm + 2176;                      // [32][65]
  const int t = threadIdx.x;
  const int tc = t & 15, tg = t >> 4;          // tc: j-quad, tg: 0..31 b-pair
  const int bb = (blockIdx.x - 1) * 64;
  const int jl = t >> 3, bc = (t & 7) * 8;     // readout mapping

  float4 s0, l0, s1, l1;
  {
    const size_t off0 = (size_t)(bb + 2 * tg) * NN + 4 * tc;
    s0 = *(const float4*)(sig + off0); l0 = *(const float4*)(lsh + off0);
    s1 = *(const float4*)(sig + off0 + NN); l1 = *(const float4*)(lsh + off0 + NN);
  }
  for (int jt = 0; jt < 8; ++jt) {
    const int j0 = jt * 64;
    float r00 = __expf(s0.x - l0.x), r01 = __expf(s0.y - l0.y);
    float r02 = __expf(s0.z - l0.z), r03 = __expf(s0.w - l0.w);
    float r10 = __expf(s1.x - l1.x), r11 = __expf(s1.y - l1.y);
    float r12 = __expf(s1.z - l1.z), r13 = __expf(s1.w - l1.w);
    if (jt < 7) {  // prefetch next chunk before the barrier
      const size_t off0 = (size_t)(bb + 2 * tg) * NN + (j0 + 64) + 4 * tc;
      s0 = *(const float4*)(sig + off0); l0 = *(const float4*)(lsh + off0);
      s1 = *(const float4*)(sig + off0 + NN); l1 = *(const float4*)(lsh + off0 + NN);
    }
    scr[tg * 65 + 4 * tc + 0] = r00 + r10;
    scr[tg * 65 + 4 * tc + 1] = r01 + r11;
    scr[tg * 65 + 4 * tc + 2] = r02 + r12;
    scr[tg * 65 + 4 * tc + 3] = r03 + r13;
    *(unsigned int*)(tile + (4 * tc + 0) * 68 + 2 * tg) = (unsigned)f2bf(r00) | ((unsigned)f2bf(r10) << 16);
    *(unsigned int*)(tile + (4 * tc + 1) * 68 + 2 * tg) = (unsigned)f2bf(r01) | ((unsigned)f2bf(r11) << 16);
    *(unsigned int*)(tile + (4 * tc + 2) * 68 + 2 * tg) = (unsigned)f2bf(r02) | ((unsigned)f2bf(r12) << 16);
    *(unsigned int*)(tile + (4 * tc + 3) * 68 + 2 * tg) = (unsigned)f2bf(r03) | ((unsigned)f2bf(r13) << 16);
    __syncthreads();
    {
      const uint2* tp = (const uint2*)(tile + jl * 68 + bc);
      uint2 a = tp[0], b = tp[1];
      *(uint4*)(Rt + (size_t)(j0 + jl) * BB + bb + bc) = make_uint4(a.x, a.y, b.x, b.y);
    }
    if (t < 64) {
      float s = 0;
#pragma unroll
      for (int g = 0; g < 32; ++g) s += scr[g * 65 + t];
      atomicAdd(&colsum[(blockIdx.x & 7) * NN + j0 + t], s);
    }
    __syncthreads();
  }
}

// K2: Cpart[kc] = Rt_i_panel * Rt_j_panel^T over K-chunk, bf16 MFMA, 8 waves; block 0: CG phase 2.
__global__ __launch_bounds__(512) void k2_syrk(
    const unsigned short* __restrict__ Rt, const float* __restrict__ Gamma,
    float* __restrict__ Cpart, float* __restrict__ cgst, float* __restrict__ v_out,
    int npart) {
  __shared__ __align__(16) unsigned short smem[16384];  // As[128][64], Bs[128][64]
  if (blockIdx.x == 0) {
    cg_phase(Gamma, nullptr, cgst, v_out, (float*)smem, 0, CG2);
    return;
  }
  const int t = threadIdx.x;
  const int blin = blockIdx.x - 1;
  const int tile = blin & 15, kc = blin >> 4;
  const int i0 = (tile & 3) * 128, j0 = (tile >> 2) * 128;
  const size_t b0 = (size_t)kc * 2048;
  const int lane = t & 63, wv = t >> 6;
  const int wi = (wv & 3) * 32, wj = (wv >> 2) * 64;  // wave tile: 32 rows x 64 cols
  const int lm = lane & 15, lq = lane >> 4;
  unsigned short* As = smem;
  unsigned short* Bs = smem + 8192;
  const int srow = t >> 3, scol = (t & 7) * 8;
  f32x4 acc[2][4];
#pragma unroll
  for (int a = 0; a < 2; ++a)
#pragma unroll
    for (int b = 0; b < 4; ++b) acc[a][b] = (f32x4){0.f, 0.f, 0.f, 0.f};

  for (int ks = 0; ks < 32; ++ks) {
    const size_t bcur = b0 + ks * 64;
    gld_lds16(Rt + (size_t)(i0 + srow) * BB + bcur + scol, As + srow * 64 + scol);
    gld_lds16(Rt + (size_t)(i0 + 64 + srow) * BB + bcur + scol, As + (64 + srow) * 64 + scol);
    gld_lds16(Rt + (size_t)(j0 + srow) * BB + bcur + scol, Bs + srow * 64 + scol);
    gld_lds16(Rt + (size_t)(j0 + 64 + srow) * BB + bcur + scol, Bs + (64 + srow) * 64 + scol);
    __syncthreads();
#pragma unroll
    for (int s = 0; s < 2; ++s) {
      bf16x8 af[2], bfr[4];
#pragma unroll
      for (int g = 0; g < 2; ++g)
        af[g] = *(const bf16x8*)(As + (wi + g * 16 + lm) * 64 + s * 32 + lq * 8);
#pragma unroll
      for (int g = 0; g < 4; ++g)
        bfr[g] = *(const bf16x8*)(Bs + (wj + g * 16 + lm) * 64 + s * 32 + lq * 8);
#pragma unroll
      for (int gm = 0; gm < 2; ++gm)
#pragma unroll
        for (int gn = 0; gn < 4; ++gn)
          acc[gm][gn] = __builtin_amdgcn_mfma_f32_16x16x32_bf16(af[gm], bfr[gn], acc[gm][gn], 0, 0, 0);
    }
    __syncthreads();
  }
  // C/D layout: col = lane&15, row = (lane>>4)*4 + reg
  float* Cw = Cpart + (npart == 1 ? (size_t)0 : (size_t)kc * NN * NN);
#pragma unroll
  for (int gm = 0; gm < 2; ++gm) {
#pragma unroll
    for (int gn = 0; gn < 4; ++gn) {
      const int col = j0 + wj + gn * 16 + lm;
#pragma unroll
      for (int e = 0; e < 4; ++e) {
        const int row = i0 + wi + gm * 16 + lq * 4 + e;
        if (npart == 1) atomicAdd(&Cw[(size_t)row * NN + col], acc[gm][gn][e]);
        else Cw[(size_t)row * NN + col] = acc[gm][gn][e];
      }
    }
  }
}

// K3: secondsum = sum_ij v_i Gamma_ij v_j (sum_p Cpart[p][i][j])
__global__ __launch_bounds__(256) void k3_contract(
    const float* __restrict__ Gamma, const float* __restrict__ Cpart,
    const float* __restrict__ v, float* __restrict__ secondsum, int npart) {
  __shared__ float red[4];
  const int t = threadIdx.x;
  const size_t e = ((size_t)blockIdx.x * 256 + t) * 4;
  const int i = (int)(e >> 9), j = (int)(e & 511);
  float cx = 0, cy = 0, cz = 0, cw = 0;
  for (int pp = 0; pp < npart; ++pp) {
    float4 c = *(const float4*)(Cpart + (size_t)pp * NN * NN + e);
    cx += c.x; cy += c.y; cz += c.z; cw += c.w;
  }
  float4 g = *(const float4*)(Gamma + e);
  float4 vj = *(const float4*)(v + j);
  float vi = v[i];
  float p = vi * (g.x * cx * vj.x + g.y * cy * vj.y + g.z * cz * vj.z + g.w * cw * vj.w);
  p = wave_reduce(p);
  if ((t & 63) == 0) red[t >> 6] = p;
  __syncthreads();
  if (t == 0) atomicAdd(secondsum, red[0] + red[1] + red[2] + red[3]);
}

// K4: loss = -( sum_j (colsum_j/B) v_j SR_j / k - secondsum/(B*2k) )
__global__ __launch_bounds__(512) void k4_final(
    const float* __restrict__ colsum, const float* __restrict__ v,
    const float* __restrict__ SR, const float* __restrict__ secondsum,
    const int* __restrict__ kp, float* __restrict__ out) {
  __shared__ float red[8];
  const int t = threadIdx.x;
  float cs = 0;
#pragma unroll
  for (int bk = 0; bk < 8; ++bk) cs += colsum[bk * NN + t];
  float f = (cs * (1.0f / BB)) * v[t] * SR[t];
  f = wave_reduce(f);
  if ((t & 63) == 0) red[t >> 6] = f;
  __syncthreads();
  if (t == 0) {
    float first = 0;
#pragma unroll
    for (int i = 0; i < 8; ++i) first += red[i];
    float kk = (float)kp[0];
    float sec = secondsum[0] / ((float)BB * 2.0f * kk);
    out[0] = -(first / kk - sec);
  }
}

extern "C" void kernel_launch(void* const* d_in, const int* in_sizes, int n_in,
                              void* d_out, int out_size, void* d_ws, size_t ws_size,
                              hipStream_t stream) {
  const float* lsh = (const float*)d_in[0];
  const float* sig = (const float*)d_in[1];
  const float* SR = (const float*)d_in[2];
  const float* Gam = (const float*)d_in[3];
  const int* kp = (const int*)d_in[4];
  char* ws = (char*)d_ws;
  const int npart = (ws_size >= ((size_t)50 << 20)) ? 16 : 1;
  float* Cpart = (float*)ws;
  const size_t small_off = (size_t)npart * NN * NN * sizeof(float);
  float* colsum = (float*)(ws + small_off);      // 8*512 floats
  float* secsum = colsum + 8 * NN;               // 1 float (padded)
  float* cgst = secsum + 64;                     // x,r,p,rr: 1537 floats
  float* v = cgst + 1664;                        // 512 floats
  unsigned short* Rt = (unsigned short*)(ws + small_off + (1 << 20));  // 32 MB

  hipMemsetAsync(colsum, 0, (8 * NN + 64) * sizeof(float), stream);
  if (npart == 1) hipMemsetAsync(Cpart, 0, (size_t)NN * NN * sizeof(float), stream);
  k1_rexp<<<513, 512, 0, stream>>>(lsh, sig, SR, Gam, Rt, colsum, cgst);
  k2_syrk<<<257, 512, 0, stream>>>(Rt, Gam, Cpart, cgst, v, npart);
  k3_contract<<<256, 256, 0, stream>>>(Gam, Cpart, v, secsum, npart);
  k4_final<<<1, 512, 0, stream>>>(colsum, v, SR, secsum, kp, (float*)d_out);
}

// Round 3
// 274.540 us; speedup vs baseline: 1.7344x; 1.0833x over previous
//
#include <hip/hip_runtime.h>
#include <hip/hip_bf16.h>
#include <stdint.h>

#define BB 32768
#define NN 512
#define CG1 4
#define CG2 6

typedef __attribute__((ext_vector_type(8))) short bf16x8;
typedef __attribute__((ext_vector_type(4))) float f32x4;

__device__ __forceinline__ void gld_lds16(const void* g, void* l) {
  typedef __attribute__((address_space(1))) const unsigned int gas_u32;
  typedef __attribute__((address_space(3))) unsigned int las_u32;
  __builtin_amdgcn_global_load_lds((gas_u32*)(uintptr_t)g,
                                   (las_u32*)(uint32_t)(uintptr_t)l, 16, 0, 0);
}

__device__ __forceinline__ unsigned short f2bf(float x) {
  __hip_bfloat16 h = __float2bfloat16(x);
  return *reinterpret_cast<unsigned short*>(&h);
}

__device__ __forceinline__ float bf2f(unsigned short u) {
  return __uint_as_float(((unsigned)u) << 16);
}

__device__ __forceinline__ float wave_reduce(float v) {
#pragma unroll
  for (int off = 32; off > 0; off >>= 1) v += __shfl_xor(v, off, 64);
  return v;
}

__device__ __forceinline__ float block_reduce(float v, float* red) {
  v = wave_reduce(v);
  const int wv = threadIdx.x >> 6, ln = threadIdx.x & 63;
  if (ln == 0) red[wv] = v;
  __syncthreads();
  if (threadIdx.x == 0) {
    float a = 0;
#pragma unroll
    for (int i = 0; i < 8; ++i) a += red[i];
    red[8] = a;
  }
  __syncthreads();
  return red[8];
}

// CG on Gamma v = SR. 512 threads, symmetric-Gamma column-major coalesced matvec.
// USEBF=1 reads bf16 Gamma copy (half the bytes; ~0.3% rel floor, fine vs 2% threshold).
// sm needs 2576 floats.
template <int USEBF>
__device__ void cg_phase(const float* __restrict__ Gamma, const unsigned short* __restrict__ Gbf,
                         const float* __restrict__ SR,
                         float* __restrict__ st, float* __restrict__ v_out,
                         float* sm, int first, int iters) {
  float* sp = sm;
  float* apw = sm + 512;
  float* red = sm + 2560;
  const int t = threadIdx.x;
  const int rg = t >> 7;         // 0..3, wave-uniform
  const int c0 = (t & 127) * 4;  // 4 columns owned
  float x, r, p, rr;
  if (first) {
    float s = SR[t];
    x = 0.f; r = s; p = s;
    rr = block_reduce(s * s, red);
  } else {
    x = st[t]; r = st[512 + t]; p = st[1024 + t]; rr = st[1536];
  }
  for (int it = 0; it < iters; ++it) {
    sp[t] = p;
    __syncthreads();
    float a0 = 0, a1 = 0, a2 = 0, a3 = 0;
    for (int j = 0; j < NN; j += 32) {
#pragma unroll
      for (int jj = 0; jj < 8; ++jj) {
        const int row = j + jj * 4 + rg;
        float g0, g1, g2, g3;
        if (USEBF) {
          ushort4 u = *(const ushort4*)(Gbf + row * NN + c0);
          g0 = bf2f(u.x); g1 = bf2f(u.y); g2 = bf2f(u.z); g3 = bf2f(u.w);
        } else {
          float4 g = *(const float4*)(Gamma + row * NN + c0);
          g0 = g.x; g1 = g.y; g2 = g.z; g3 = g.w;
        }
        float pv = sp[row];
        a0 += g0 * pv; a1 += g1 * pv; a2 += g2 * pv; a3 += g3 * pv;
      }
    }
    *(float4*)(apw + rg * 512 + c0) = make_float4(a0, a1, a2, a3);
    __syncthreads();
    float ap = apw[t] + apw[512 + t] + apw[1024 + t] + apw[1536 + t];
    float pAp = block_reduce(p * ap, red);
    float alpha = rr / pAp;
    x += alpha * p;
    r -= alpha * ap;
    float rrn = block_reduce(r * r, red);
    float beta = rrn / rr;
    p = r + beta * p;
    rr = rrn;
    __syncthreads();
  }
  if (v_out) {
    v_out[t] = x;
  } else {
    st[t] = x; st[512 + t] = r; st[1024 + t] = p;
    if (t == 0) st[1536] = rr;
  }
}

// K1: blocks 1..512: r = exp(sigma-lsh) -> bf16 transposed Rt[N][B] + colsums.
//     block 0: CG phase 1 (4 fp32 iters). blocks 513..516: Gamma -> bf16 copy.
__global__ __launch_bounds__(512) void k1_rexp(
    const float* __restrict__ lsh, const float* __restrict__ sig,
    const float* __restrict__ SR, const float* __restrict__ Gamma,
    unsigned short* __restrict__ Rt, float* __restrict__ colsum,
    float* __restrict__ cgst, unsigned short* __restrict__ Gbf) {
  __shared__ __align__(16) float sm[4352];
  if (blockIdx.x == 0) {
    cg_phase<0>(Gamma, nullptr, SR, cgst, nullptr, sm, 1, CG1);
    return;
  }
  if (blockIdx.x >= 513) {  // Gamma -> bf16 (128 rows per block)
    const int b = blockIdx.x - 513;
    const float4* src = (const float4*)(Gamma + (size_t)b * 128 * NN);
    ushort4* dst = (ushort4*)(Gbf + (size_t)b * 128 * NN);
    for (int i = threadIdx.x; i < 16384; i += 512) {
      float4 g = src[i];
      dst[i] = make_ushort4(f2bf(g.x), f2bf(g.y), f2bf(g.z), f2bf(g.w));
    }
    return;
  }
  unsigned short* tile = (unsigned short*)sm;  // [64 j][68 b] ushort
  float* scr = sm + 2176;                      // [32][65]
  const int t = threadIdx.x;
  const int tc = t & 15, tg = t >> 4;          // tc: j-quad, tg: b-pair group
  const int bb = (blockIdx.x - 1) * 64;
  const int jl = t >> 3, bc = (t & 7) * 8;     // readout mapping

  float4 s0, l0, s1, l1;
  {
    const size_t off0 = (size_t)(bb + 2 * tg) * NN + 4 * tc;
    s0 = *(const float4*)(sig + off0); l0 = *(const float4*)(lsh + off0);
    s1 = *(const float4*)(sig + off0 + NN); l1 = *(const float4*)(lsh + off0 + NN);
  }
  for (int jt = 0; jt < 8; ++jt) {
    const int j0 = jt * 64;
    float r00 = __expf(s0.x - l0.x), r01 = __expf(s0.y - l0.y);
    float r02 = __expf(s0.z - l0.z), r03 = __expf(s0.w - l0.w);
    float r10 = __expf(s1.x - l1.x), r11 = __expf(s1.y - l1.y);
    float r12 = __expf(s1.z - l1.z), r13 = __expf(s1.w - l1.w);
    if (jt < 7) {
      const size_t off0 = (size_t)(bb + 2 * tg) * NN + (j0 + 64) + 4 * tc;
      s0 = *(const float4*)(sig + off0); l0 = *(const float4*)(lsh + off0);
      s1 = *(const float4*)(sig + off0 + NN); l1 = *(const float4*)(lsh + off0 + NN);
    }
    scr[tg * 65 + 4 * tc + 0] = r00 + r10;
    scr[tg * 65 + 4 * tc + 1] = r01 + r11;
    scr[tg * 65 + 4 * tc + 2] = r02 + r12;
    scr[tg * 65 + 4 * tc + 3] = r03 + r13;
    *(unsigned int*)(tile + (4 * tc + 0) * 68 + 2 * tg) = (unsigned)f2bf(r00) | ((unsigned)f2bf(r10) << 16);
    *(unsigned int*)(tile + (4 * tc + 1) * 68 + 2 * tg) = (unsigned)f2bf(r01) | ((unsigned)f2bf(r11) << 16);
    *(unsigned int*)(tile + (4 * tc + 2) * 68 + 2 * tg) = (unsigned)f2bf(r02) | ((unsigned)f2bf(r12) << 16);
    *(unsigned int*)(tile + (4 * tc + 3) * 68 + 2 * tg) = (unsigned)f2bf(r03) | ((unsigned)f2bf(r13) << 16);
    __syncthreads();
    {
      const uint2* tp = (const uint2*)(tile + jl * 68 + bc);
      uint2 a = tp[0], b = tp[1];
      *(uint4*)(Rt + (size_t)(j0 + jl) * BB + bb + bc) = make_uint4(a.x, a.y, b.x, b.y);
    }
    if (t < 64) {
      float s = 0;
#pragma unroll
      for (int g = 0; g < 32; ++g) s += scr[g * 65 + t];
      atomicAdd(&colsum[(blockIdx.x & 7) * NN + j0 + t], s);
    }
    __syncthreads();
  }
}

// K2: blocks 1..512: Cpart[kc] += Rt_i * Rt_j^T over 1024-wide K-chunk (bf16 MFMA).
//     block 0: CG phase 2 (6 bf16 iters) -> v.
__global__ __launch_bounds__(512) void k2_syrk(
    const unsigned short* __restrict__ Rt, const float* __restrict__ Gamma,
    const unsigned short* __restrict__ Gbf,
    float* __restrict__ Cpart, float* __restrict__ cgst, float* __restrict__ v_out,
    int npart) {
  __shared__ __align__(16) unsigned short smem[16384];  // As[128][64], Bs[128][64]
  if (blockIdx.x == 0) {
    cg_phase<1>(Gamma, Gbf, nullptr, cgst, v_out, (float*)smem, 0, CG2);
    return;
  }
  const int t = threadIdx.x;
  const int blin = blockIdx.x - 1;
  const int tile = blin & 15, kc = blin >> 4;          // kc in 0..31
  const int i0 = (tile & 3) * 128, j0 = (tile >> 2) * 128;
  const size_t b0 = (size_t)kc * 1024;
  const int lane = t & 63, wv = t >> 6;
  const int wi = (wv & 3) * 32, wj = (wv >> 2) * 64;
  const int lm = lane & 15, lq = lane >> 4;
  unsigned short* As = smem;
  unsigned short* Bs = smem + 8192;
  const int srow = t >> 3, scol = (t & 7) * 8;
  f32x4 acc[2][4];
#pragma unroll
  for (int a = 0; a < 2; ++a)
#pragma unroll
    for (int b = 0; b < 4; ++b) acc[a][b] = (f32x4){0.f, 0.f, 0.f, 0.f};

  for (int ks = 0; ks < 16; ++ks) {
    const size_t bcur = b0 + ks * 64;
    gld_lds16(Rt + (size_t)(i0 + srow) * BB + bcur + scol, As + srow * 64 + scol);
    gld_lds16(Rt + (size_t)(i0 + 64 + srow) * BB + bcur + scol, As + (64 + srow) * 64 + scol);
    gld_lds16(Rt + (size_t)(j0 + srow) * BB + bcur + scol, Bs + srow * 64 + scol);
    gld_lds16(Rt + (size_t)(j0 + 64 + srow) * BB + bcur + scol, Bs + (64 + srow) * 64 + scol);
    __syncthreads();
#pragma unroll
    for (int s = 0; s < 2; ++s) {
      bf16x8 af[2], bfr[4];
#pragma unroll
      for (int g = 0; g < 2; ++g)
        af[g] = *(const bf16x8*)(As + (wi + g * 16 + lm) * 64 + s * 32 + lq * 8);
#pragma unroll
      for (int g = 0; g < 4; ++g)
        bfr[g] = *(const bf16x8*)(Bs + (wj + g * 16 + lm) * 64 + s * 32 + lq * 8);
#pragma unroll
      for (int gm = 0; gm < 2; ++gm)
#pragma unroll
        for (int gn = 0; gn < 4; ++gn)
          acc[gm][gn] = __builtin_amdgcn_mfma_f32_16x16x32_bf16(af[gm], bfr[gn], acc[gm][gn], 0, 0, 0);
    }
    __syncthreads();
  }
  // C/D layout: col = lane&15, row = (lane>>4)*4 + reg
  float* Cw = Cpart + (npart == 1 ? (size_t)0 : (size_t)kc * NN * NN);
#pragma unroll
  for (int gm = 0; gm < 2; ++gm) {
#pragma unroll
    for (int gn = 0; gn < 4; ++gn) {
      const int col = j0 + wj + gn * 16 + lm;
#pragma unroll
      for (int e = 0; e < 4; ++e) {
        const int row = i0 + wi + gm * 16 + lq * 4 + e;
        if (npart == 1) atomicAdd(&Cw[(size_t)row * NN + col], acc[gm][gn][e]);
        else Cw[(size_t)row * NN + col] = acc[gm][gn][e];
      }
    }
  }
}

// K3: secondsum = sum_ij v_i Gamma_ij v_j (sum_p Cpart[p][i][j])
__global__ __launch_bounds__(256) void k3_contract(
    const float* __restrict__ Gamma, const float* __restrict__ Cpart,
    const float* __restrict__ v, float* __restrict__ secondsum, int npart) {
  __shared__ float red[4];
  const int t = threadIdx.x;
  const size_t e = ((size_t)blockIdx.x * 256 + t) * 4;
  const int i = (int)(e >> 9), j = (int)(e & 511);
  float cx = 0, cy = 0, cz = 0, cw = 0;
  for (int pp = 0; pp < npart; ++pp) {
    float4 c = *(const float4*)(Cpart + (size_t)pp * NN * NN + e);
    cx += c.x; cy += c.y; cz += c.z; cw += c.w;
  }
  float4 g = *(const float4*)(Gamma + e);
  float4 vj = *(const float4*)(v + j);
  float vi = v[i];
  float p = vi * (g.x * cx * vj.x + g.y * cy * vj.y + g.z * cz * vj.z + g.w * cw * vj.w);
  p = wave_reduce(p);
  if ((t & 63) == 0) red[t >> 6] = p;
  __syncthreads();
  if (t == 0) atomicAdd(secondsum, red[0] + red[1] + red[2] + red[3]);
}

// K4: loss = -( sum_j (colsum_j/B) v_j SR_j / k - secondsum/(B*2k) )
__global__ __launch_bounds__(512) void k4_final(
    const float* __restrict__ colsum, const float* __restrict__ v,
    const float* __restrict__ SR, const float* __restrict__ secondsum,
    const int* __restrict__ kp, float* __restrict__ out) {
  __shared__ float red[8];
  const int t = threadIdx.x;
  float cs = 0;
#pragma unroll
  for (int bk = 0; bk < 8; ++bk) cs += colsum[bk * NN + t];
  float f = (cs * (1.0f / BB)) * v[t] * SR[t];
  f = wave_reduce(f);
  if ((t & 63) == 0) red[t >> 6] = f;
  __syncthreads();
  if (t == 0) {
    float first = 0;
#pragma unroll
    for (int i = 0; i < 8; ++i) first += red[i];
    float kk = (float)kp[0];
    float sec = secondsum[0] / ((float)BB * 2.0f * kk);
    out[0] = -(first / kk - sec);
  }
}

extern "C" void kernel_launch(void* const* d_in, const int* in_sizes, int n_in,
                              void* d_out, int out_size, void* d_ws, size_t ws_size,
                              hipStream_t stream) {
  const float* lsh = (const float*)d_in[0];
  const float* sig = (const float*)d_in[1];
  const float* SR = (const float*)d_in[2];
  const float* Gam = (const float*)d_in[3];
  const int* kp = (const int*)d_in[4];
  char* ws = (char*)d_ws;
  const int npart = (ws_size >= ((size_t)67 << 20)) ? 32 : 1;
  float* Cpart = (float*)ws;
  const size_t coff = (size_t)npart * NN * NN * sizeof(float);
  float* colsum = (float*)(ws + coff);                       // 8*512 floats
  float* secsum = colsum + 8 * NN;                           // 1 float (padded 64)
  float* cgst = secsum + 64;                                 // 1537 floats (padded 1664)
  float* v = cgst + 1664;                                    // 512 floats
  unsigned short* Gbf = (unsigned short*)(ws + coff + (64 << 10));   // 512 KB
  unsigned short* Rt = (unsigned short*)(ws + coff + (64 << 10) + (512 << 10));  // 32 MB

  hipMemsetAsync(colsum, 0, (8 * NN + 64) * sizeof(float), stream);
  if (npart == 1) hipMemsetAsync(Cpart, 0, (size_t)NN * NN * sizeof(float), stream);
  k1_rexp<<<517, 512, 0, stream>>>(lsh, sig, SR, Gam, Rt, colsum, cgst, Gbf);
  k2_syrk<<<513, 512, 0, stream>>>(Rt, Gam, Gbf, Cpart, cgst, v, npart);
  k3_contract<<<256, 256, 0, stream>>>(Gam, Cpart, v, secsum, npart);
  k4_final<<<1, 512, 0, stream>>>(colsum, v, SR, secsum, kp, (float*)d_out);
}

// Round 4
// 227.481 us; speedup vs baseline: 2.0932x; 1.2069x over previous
//
#include <hip/hip_runtime.h>
#include <hip/hip_bf16.h>
#include <stdint.h>

#define BB 32768
#define NN 512
#define CG1 4
#define CG2 3
#define NPART 64
#define NTILE 10

typedef __attribute__((ext_vector_type(8))) short bf16x8;
typedef __attribute__((ext_vector_type(4))) float f32x4;

__device__ __forceinline__ void gld_lds16(const void* g, void* l) {
  typedef __attribute__((address_space(1))) const unsigned int gas_u32;
  typedef __attribute__((address_space(3))) unsigned int las_u32;
  __builtin_amdgcn_global_load_lds((gas_u32*)(uintptr_t)g,
                                   (las_u32*)(uint32_t)(uintptr_t)l, 16, 0, 0);
}

__device__ __forceinline__ unsigned short f2bf(float x) {
  __hip_bfloat16 h = __float2bfloat16(x);
  return *reinterpret_cast<unsigned short*>(&h);
}

__device__ __forceinline__ float bf2f(unsigned short u) {
  return __uint_as_float(((unsigned)u) << 16);
}

__device__ __forceinline__ float wave_reduce(float v) {
#pragma unroll
  for (int off = 32; off > 0; off >>= 1) v += __shfl_xor(v, off, 64);
  return v;
}

__device__ __forceinline__ float block_reduce(float v, float* red) {
  v = wave_reduce(v);
  const int wv = threadIdx.x >> 6, ln = threadIdx.x & 63;
  if (ln == 0) red[wv] = v;
  __syncthreads();
  if (threadIdx.x == 0) {
    float a = 0;
#pragma unroll
    for (int i = 0; i < 8; ++i) a += red[i];
    red[8] = a;
  }
  __syncthreads();
  return red[8];
}

// CG on Gamma v = SR, bf16 Gamma, 512 threads, symmetric column-major matvec.
// sm needs 2576 floats.
__device__ void cg_phase(const unsigned short* __restrict__ Gbf, const float* __restrict__ SR,
                         float* __restrict__ st, float* __restrict__ v_out,
                         float* sm, int first, int iters) {
  float* sp = sm;
  float* apw = sm + 512;
  float* red = sm + 2560;
  const int t = threadIdx.x;
  const int rg = t >> 7;         // 0..3, wave-uniform
  const int c0 = (t & 127) * 4;  // 4 columns owned
  float x, r, p, rr;
  if (first) {
    float s = SR[t];
    x = 0.f; r = s; p = s;
    rr = block_reduce(s * s, red);
  } else {
    x = st[t]; r = st[512 + t]; p = st[1024 + t]; rr = st[1536];
  }
  for (int it = 0; it < iters; ++it) {
    sp[t] = p;
    __syncthreads();
    float a0 = 0, a1 = 0, a2 = 0, a3 = 0;
    for (int j = 0; j < NN; j += 32) {
#pragma unroll
      for (int jj = 0; jj < 8; ++jj) {
        const int row = j + jj * 4 + rg;
        ushort4 u = *(const ushort4*)(Gbf + row * NN + c0);
        float pv = sp[row];
        a0 += bf2f(u.x) * pv; a1 += bf2f(u.y) * pv;
        a2 += bf2f(u.z) * pv; a3 += bf2f(u.w) * pv;
      }
    }
    *(float4*)(apw + rg * 512 + c0) = make_float4(a0, a1, a2, a3);
    __syncthreads();
    float ap = apw[t] + apw[512 + t] + apw[1024 + t] + apw[1536 + t];
    float pAp = block_reduce(p * ap, red);
    float alpha = rr / pAp;
    x += alpha * p;
    r -= alpha * ap;
    float rrn = block_reduce(r * r, red);
    float beta = rrn / rr;
    p = r + beta * p;
    rr = rrn;
    __syncthreads();
  }
  if (v_out) {
    v_out[t] = x;
  } else {
    st[t] = x; st[512 + t] = r; st[1024 + t] = p;
    if (t == 0) st[1536] = rr;
  }
}

// K0: Gamma -> bf16 copy; block 0 also zeros colsum+secsum.
__global__ __launch_bounds__(256) void k0_prep(
    const float* __restrict__ Gam, unsigned short* __restrict__ Gbf,
    float* __restrict__ small_zero) {  // colsum[4096] + secsum[64] contiguous
  const int t = threadIdx.x, b = blockIdx.x;
  const size_t base = ((size_t)b * 256 + t) * 8;
  float4 g0 = *(const float4*)(Gam + base);
  float4 g1 = *(const float4*)(Gam + base + 4);
  *(ushort4*)(Gbf + base) = make_ushort4(f2bf(g0.x), f2bf(g0.y), f2bf(g0.z), f2bf(g0.w));
  *(ushort4*)(Gbf + base + 4) = make_ushort4(f2bf(g1.x), f2bf(g1.y), f2bf(g1.z), f2bf(g1.w));
  if (b == 0)
    for (int i = t; i < 4160; i += 256) small_zero[i] = 0.f;
}

// K1: blocks 1..1024: r = exp(sigma-lsh) -> bf16 transposed Rt[N][B] + colsum buckets.
//     block 0: CG phase 1 (4 bf16 iters).
__global__ __launch_bounds__(512) void k1_rexp(
    const float* __restrict__ lsh, const float* __restrict__ sig,
    const float* __restrict__ SR, const unsigned short* __restrict__ Gbf,
    unsigned short* __restrict__ Rt, float* __restrict__ colsum,
    float* __restrict__ cgst) {
  __shared__ __align__(16) float sm[3392];
  if (blockIdx.x == 0) {
    cg_phase(Gbf, SR, cgst, nullptr, sm, 1, CG1);
    return;
  }
  unsigned short* tile = (unsigned short*)sm;  // [64 j][36 b] ushort = 1152 floats
  float* scr = sm + 1152;                      // [32][68] floats
  const int t = threadIdx.x;
  const int tc = t & 15, tg = t >> 4;          // tc: j-quad, tg: b-row 0..31
  const int wb = blockIdx.x - 1;
  const int bb = wb * 32;
  const int jl = t >> 3, bc = (t & 7) * 4;     // readout: 64 j x 8 b-quads
  for (int jt = 0; jt < 8; ++jt) {
    const int j0 = jt * 64;
    const size_t off = (size_t)(bb + tg) * NN + j0 + 4 * tc;
    float4 sv = *(const float4*)(sig + off);
    float4 lv = *(const float4*)(lsh + off);
    float r0 = __expf(sv.x - lv.x), r1 = __expf(sv.y - lv.y);
    float r2 = __expf(sv.z - lv.z), r3 = __expf(sv.w - lv.w);
    scr[tg * 68 + 4 * tc + 0] = r0;
    scr[tg * 68 + 4 * tc + 1] = r1;
    scr[tg * 68 + 4 * tc + 2] = r2;
    scr[tg * 68 + 4 * tc + 3] = r3;
    tile[(4 * tc + 0) * 36 + tg] = f2bf(r0);
    tile[(4 * tc + 1) * 36 + tg] = f2bf(r1);
    tile[(4 * tc + 2) * 36 + tg] = f2bf(r2);
    tile[(4 * tc + 3) * 36 + tg] = f2bf(r3);
    __syncthreads();
    {
      ushort4 vv = *(const ushort4*)(tile + jl * 36 + bc);
      *(ushort4*)(Rt + (size_t)(j0 + jl) * BB + bb + bc) = vv;
    }
    if (t < 64) {
      float s = 0;
#pragma unroll
      for (int g = 0; g < 32; ++g) s += scr[g * 68 + t];
      atomicAdd(&colsum[(wb & 7) * NN + j0 + t], s);
    }
    __syncthreads();
  }
}

// K2: blocks 1..640: Cpart[kc](bf16) = Rt_i * Rt_j^T over 512-wide K-chunk, upper-triangle
//     tiles only (off-diag epilogue writes both C and C^T). block 0: CG phase 2 -> v.
__global__ __launch_bounds__(512) void k2_syrk(
    const unsigned short* __restrict__ Rt, const unsigned short* __restrict__ Gbf,
    unsigned short* __restrict__ Cpart, float* __restrict__ cgst,
    float* __restrict__ v_out) {
  __shared__ __align__(16) unsigned short smem[16384];  // As[128][64], Bs[128][64]
  if (blockIdx.x == 0) {
    cg_phase(Gbf, nullptr, cgst, v_out, (float*)smem, 0, CG2);
    return;
  }
  const int wb = blockIdx.x - 1;
  const int kc = wb / NTILE, tt = wb % NTILE;
  const int ti = (int)((0x3221110000ULL >> (4 * tt)) & 0xF);
  const int tj = (int)((0x3323213210ULL >> (4 * tt)) & 0xF);
  const int i0 = ti * 128, j0 = tj * 128;
  const int diag = (ti == tj);
  const size_t b0 = (size_t)kc * 512;
  const int t = threadIdx.x, lane = t & 63, wv = t >> 6;
  const int wi = (wv & 3) * 32, wj = (wv >> 2) * 64;
  const int lm = lane & 15, lq = lane >> 4;
  unsigned short* As = smem;
  unsigned short* Bs = diag ? smem : smem + 8192;
  const int srow = t >> 3, scol = (t & 7) * 8;
  f32x4 acc[2][4];
#pragma unroll
  for (int a = 0; a < 2; ++a)
#pragma unroll
    for (int b = 0; b < 4; ++b) acc[a][b] = (f32x4){0.f, 0.f, 0.f, 0.f};

  for (int ks = 0; ks < 8; ++ks) {
    const size_t bcur = b0 + ks * 64;
    gld_lds16(Rt + (size_t)(i0 + srow) * BB + bcur + scol, As + srow * 64 + scol);
    gld_lds16(Rt + (size_t)(i0 + 64 + srow) * BB + bcur + scol, As + (64 + srow) * 64 + scol);
    if (!diag) {
      gld_lds16(Rt + (size_t)(j0 + srow) * BB + bcur + scol, Bs + srow * 64 + scol);
      gld_lds16(Rt + (size_t)(j0 + 64 + srow) * BB + bcur + scol, Bs + (64 + srow) * 64 + scol);
    }
    __syncthreads();
#pragma unroll
    for (int s = 0; s < 2; ++s) {
      bf16x8 af[2], bfr[4];
#pragma unroll
      for (int g = 0; g < 2; ++g)
        af[g] = *(const bf16x8*)(As + (wi + g * 16 + lm) * 64 + s * 32 + lq * 8);
#pragma unroll
      for (int g = 0; g < 4; ++g)
        bfr[g] = *(const bf16x8*)(Bs + (wj + g * 16 + lm) * 64 + s * 32 + lq * 8);
#pragma unroll
      for (int gm = 0; gm < 2; ++gm)
#pragma unroll
        for (int gn = 0; gn < 4; ++gn)
          acc[gm][gn] = __builtin_amdgcn_mfma_f32_16x16x32_bf16(af[gm], bfr[gn], acc[gm][gn], 0, 0, 0);
    }
    __syncthreads();
  }
  // C/D layout: col = lane&15, row = (lane>>4)*4 + reg
  unsigned short* Cw = Cpart + (size_t)kc * NN * NN;
#pragma unroll
  for (int gm = 0; gm < 2; ++gm) {
    const int rbase = i0 + wi + gm * 16 + lq * 4;
#pragma unroll
    for (int gn = 0; gn < 4; ++gn) {
      const int col = j0 + wj + gn * 16 + lm;
      unsigned short e0 = f2bf(acc[gm][gn][0]), e1 = f2bf(acc[gm][gn][1]);
      unsigned short e2 = f2bf(acc[gm][gn][2]), e3 = f2bf(acc[gm][gn][3]);
      Cw[(size_t)(rbase + 0) * NN + col] = e0;
      Cw[(size_t)(rbase + 1) * NN + col] = e1;
      Cw[(size_t)(rbase + 2) * NN + col] = e2;
      Cw[(size_t)(rbase + 3) * NN + col] = e3;
      if (!diag)
        *(ushort4*)(Cw + (size_t)col * NN + rbase) = make_ushort4(e0, e1, e2, e3);
    }
  }
}

// K3: secondsum = sum_ij v_i Gamma_ij v_j (sum_p Cpart[p][i][j])
__global__ __launch_bounds__(256) void k3_contract(
    const float* __restrict__ Gamma, const unsigned short* __restrict__ Cpart,
    const float* __restrict__ v, float* __restrict__ secondsum) {
  __shared__ float red[4];
  const int t = threadIdx.x;
  const size_t e = ((size_t)blockIdx.x * 256 + t) * 4;
  const int i = (int)(e >> 9), j = (int)(e & 511);
  float cx = 0, cy = 0, cz = 0, cw = 0;
  for (int pp = 0; pp < NPART; ++pp) {
    ushort4 u = *(const ushort4*)(Cpart + (size_t)pp * NN * NN + e);
    cx += bf2f(u.x); cy += bf2f(u.y); cz += bf2f(u.z); cw += bf2f(u.w);
  }
  float4 g = *(const float4*)(Gamma + e);
  float4 vj = *(const float4*)(v + j);
  float vi = v[i];
  float p = vi * (g.x * cx * vj.x + g.y * cy * vj.y + g.z * cz * vj.z + g.w * cw * vj.w);
  p = wave_reduce(p);
  if ((t & 63) == 0) red[t >> 6] = p;
  __syncthreads();
  if (t == 0) atomicAdd(secondsum, red[0] + red[1] + red[2] + red[3]);
}

// K4: loss = -( sum_j (colsum_j/B) v_j SR_j / k - secondsum/(B*2k) )
__global__ __launch_bounds__(512) void k4_final(
    const float* __restrict__ colsum, const float* __restrict__ v,
    const float* __restrict__ SR, const float* __restrict__ secondsum,
    const int* __restrict__ kp, float* __restrict__ out) {
  __shared__ float red[8];
  const int t = threadIdx.x;
  float cs = 0;
#pragma unroll
  for (int bk = 0; bk < 8; ++bk) cs += colsum[bk * NN + t];
  float f = (cs * (1.0f / BB)) * v[t] * SR[t];
  f = wave_reduce(f);
  if ((t & 63) == 0) red[t >> 6] = f;
  __syncthreads();
  if (t == 0) {
    float first = 0;
#pragma unroll
    for (int i = 0; i < 8; ++i) first += red[i];
    float kk = (float)kp[0];
    float sec = secondsum[0] / ((float)BB * 2.0f * kk);
    out[0] = -(first / kk - sec);
  }
}

extern "C" void kernel_launch(void* const* d_in, const int* in_sizes, int n_in,
                              void* d_out, int out_size, void* d_ws, size_t ws_size,
                              hipStream_t stream) {
  const float* lsh = (const float*)d_in[0];
  const float* sig = (const float*)d_in[1];
  const float* SR = (const float*)d_in[2];
  const float* Gam = (const float*)d_in[3];
  const int* kp = (const int*)d_in[4];
  char* ws = (char*)d_ws;
  // layout: Cpart bf16 32MB | colsum 4096f | secsum 64f | cgst 1664f | v 512f | Gbf 512KB | Rt 32MB
  unsigned short* Cpart = (unsigned short*)ws;
  const size_t coff = (size_t)NPART * NN * NN * sizeof(unsigned short);  // 32 MB
  float* colsum = (float*)(ws + coff);
  float* secsum = colsum + 4096;
  float* cgst = secsum + 64;
  float* v = cgst + 1664;
  unsigned short* Gbf = (unsigned short*)(ws + coff + (32 << 10));
  unsigned short* Rt = (unsigned short*)(ws + coff + (32 << 10) + (512 << 10));

  k0_prep<<<128, 256, 0, stream>>>(Gam, Gbf, colsum);
  k1_rexp<<<1025, 512, 0, stream>>>(lsh, sig, SR, Gbf, Rt, colsum, cgst);
  k2_syrk<<<641, 512, 0, stream>>>(Rt, Gbf, Cpart, cgst, v);
  k3_contract<<<256, 256, 0, stream>>>(Gam, Cpart, v, secsum);
  k4_final<<<1, 512, 0, stream>>>(colsum, v, SR, secsum, kp, (float*)d_out);
}